// Round 10
// baseline (397.448 us; speedup 1.0000x reference)
//
#include <hip/hip_runtime.h>
#include <cmath>

namespace {
constexpr int NB  = 256;   // batch
constexpr int CI  = 64;    // in channels
constexpr int CO  = 64;    // out channels
constexpr int TT  = 64;    // time
constexpr int V   = 25;    // vertices
constexpr int REL = 8;     // rel channels
constexpr int TV  = TT * V;   // 1600
constexpr int CC  = 8;     // channels per fused block
constexpr int TH  = 32;    // t per half
constexpr int IP  = 28;    // inp row pad (16B-aligned rows)
constexpr int AP  = 28;    // Af row pad (16B-aligned rows)
}

typedef float f4 __attribute__((ext_vector_type(4)));

// ---------------------------------------------------------------------------
// K1: per-n temporal reduction -> x1,x2 (REL*V each) into ws. (unchanged)
// ---------------------------------------------------------------------------
__global__ __launch_bounds__(1024) void k1_x12(
    const float* __restrict__ x,
    const float* __restrict__ w1, const float* __restrict__ b1,
    const float* __restrict__ w2, const float* __restrict__ b2,
    float* __restrict__ ws) {
  const int n = blockIdx.x;
  const int tid = threadIdx.x;
  __shared__ __align__(16) float xs[8][TV];
  __shared__ float xsum[CI][V];
  __shared__ float w12[2][REL][CI];

  for (int idx = tid; idx < 2 * REL * CI; idx += 1024) {
    int half = idx / (REL * CI), rem = idx % (REL * CI);
    w12[half][rem / CI][rem % CI] = half ? w2[rem] : w1[rem];
  }

  const float4* xb = reinterpret_cast<const float4*>(x + (size_t)n * (CI * TV));
  float4* xsv = reinterpret_cast<float4*>(&xs[0][0]);
  constexpr int V4G = 8 * TV / 4;  // 3200

  for (int g = 0; g < 8; ++g) {
    __syncthreads();
    for (int idx = tid; idx < V4G; idx += 1024)
      xsv[idx] = xb[g * V4G + idx];
    __syncthreads();
    if (tid < 8 * V) {
      int ch = tid / V, v = tid % V;
      float acc = 0.f;
      #pragma unroll
      for (int t = 0; t < TT; ++t) acc += xs[ch][t * V + v];
      xsum[g * 8 + ch][v] = acc;
    }
  }
  __syncthreads();

  if (tid < 2 * REL * V) {
    int half = tid / (REL * V), rem = tid % (REL * V);
    int r = rem / V, v = rem % V;
    float a = 0.f;
    #pragma unroll
    for (int i = 0; i < CI; ++i) a = fmaf(w12[half][r][i], xsum[i][v], a);
    ws[(size_t)n * (2 * REL * V) + tid] = a * (1.f / TT) + (half ? b2[r] : b1[r]);
  }
}

// ---------------------------------------------------------------------------
// K2 fused. Changes vs R9:
//  - P2 on 256 threads with acc[4][7] (t-rows tq+8*ti): 11 LDS reads / 112 FMA
//    per chunk -> DS-pipe load per block-half nearly halves.
//  - P1 software-pipelined in 8-i register chunks; chunk-0 loads hoisted
//    (h=0: to kernel top, hidden under P0; h=1: before P2(0), hidden under
//    P2 compute). Clean-store pattern of R9 kept.
// LDS 53152 B -> 3 blocks/CU. __launch_bounds__(512,6): VGPR cap 85.
// ---------------------------------------------------------------------------
__global__ __launch_bounds__(512, 6) void k2_fused(
    const float* __restrict__ x, const float* __restrict__ A,
    const float* __restrict__ w3, const float* __restrict__ b3,
    const float* __restrict__ wr, const float* __restrict__ br,
    const float* __restrict__ ws, float* __restrict__ out) {
  const int id  = blockIdx.x;
  const int n   = (id & 7) | ((id >> 3) & ~7);
  const int cb  = (id >> 3) & 7;
  const int c0  = cb * CC;
  const int tid = threadIdx.x;       // 0..511

  __shared__ __align__(16) float inp[CC * TH * IP];   // 28672 B
  __shared__ __align__(16) float Afs[CC * V * AP];    // 22400 B
  __shared__ __align__(16) float wrs[CI * CC + CC];   // 2080 B (wr^T chunk + br)

  const bool p1w = tid < TH * V / 2;                  // 400 P1 workers
  const float* xp = x + (size_t)n * (CI * TV) + tid * 2;

  // ---- hoisted loads: h=0, i-chunk 0 (in flight under P0a+P0b)
  float2 xv[8];
  if (p1w) {
    #pragma unroll
    for (int j = 0; j < 8; ++j)
      xv[j] = *reinterpret_cast<const float2*>(xp + (size_t)j * TV);
  }

  // ---- P0a: zero inp (pad cols v>=25 stay 0 forever), stage wr^T (+ br)
  {
    f4* iz = reinterpret_cast<f4*>(inp);
    #pragma unroll
    for (int k = 0; k < 4; ++k) {                      // 1792 f4
      int idx = tid + k * 512;
      if (idx < CC * TH * IP / 4) iz[idx] = (f4)0.f;
    }
    int i = tid >> 3, cc = tid & 7;                    // tid < 512 == CI*CC
    wrs[i * CC + cc] = wr[(size_t)(c0 + cc) * CI + i];
    if (tid < CC) wrs[CI * CC + tid] = br[c0 + tid];
  }

  // ---- P0b: Af[cc][u][v] = A[u][v]+b3[c]+sum_r w3[c][r]*tanh(x1[r][u]-x2[r][v])
  const float* x1n = ws + (size_t)n * (2 * REL * V);
  const float* x2n = x1n + REL * V;
  for (int idx = tid; idx < V * AP; idx += 512) {      // 700 tasks
    int u = idx / AP, v = idx % AP;
    if (v < V) {
      float t8[REL];
      #pragma unroll
      for (int r = 0; r < REL; ++r)
        t8[r] = tanhf(x1n[r * V + u] - x2n[r * V + v]);
      const float base = A[u * V + v];
      #pragma unroll
      for (int cc = 0; cc < CC; ++cc) {
        float acc = base + b3[c0 + cc];
        #pragma unroll
        for (int r = 0; r < REL; ++r)
          acc = fmaf(w3[(c0 + cc) * REL + r], t8[r], acc);
        Afs[(cc * V + u) * AP + v] = acc;
      }
    } else {
      #pragma unroll
      for (int cc = 0; cc < CC; ++cc)
        Afs[(cc * V + u) * AP + v] = 0.f;
    }
  }
  __syncthreads();

  // P2 mapping (tid < 256): cc(8) x tq(8) x uq(4); t-rows tq+8*ti; u0=6*uq
  const int cc2 = tid >> 5;
  const int tq  = (tid >> 2) & 7;
  const int uq  = tid & 3;
  const int u0  = uq * 6;             // overlap at 6/12/18: benign dup stores

  #pragma unroll
  for (int h = 0; h < 2; ++h) {
    // ---- P1h: inp[cc][tloc][v], tloc in [0,32). 400 float2-columns.
    //      software pipeline: 8 chunks of 8 i, double-buffered registers.
    if (p1w) {
      float accp[CC][2];
      #pragma unroll
      for (int c = 0; c < CC; ++c) {
        float b = wrs[CI * CC + c];
        accp[c][0] = b; accp[c][1] = b;
      }
      const float* xph = xp + h * (TH * V);
      #pragma unroll
      for (int chn = 0; chn < 8; ++chn) {
        float2 xn[8];
        if (chn < 7) {
          #pragma unroll
          for (int j = 0; j < 8; ++j)
            xn[j] = *reinterpret_cast<const float2*>(xph + (size_t)((chn + 1) * 8 + j) * TV);
        }
        #pragma unroll
        for (int j = 0; j < 8; ++j) {
          const int i = chn * 8 + j;
          float4 wa = *reinterpret_cast<const float4*>(&wrs[i * CC]);      // bcast
          float4 wb = *reinterpret_cast<const float4*>(&wrs[i * CC + 4]);  // bcast
          float w8[8] = {wa.x, wa.y, wa.z, wa.w, wb.x, wb.y, wb.z, wb.w};
          #pragma unroll
          for (int c = 0; c < CC; ++c) {
            accp[c][0] = fmaf(w8[c], xv[j].x, accp[c][0]);
            accp[c][1] = fmaf(w8[c], xv[j].y, accp[c][1]);
          }
        }
        #pragma unroll
        for (int j = 0; j < 8; ++j) xv[j] = xn[j];
      }
      int tv0 = tid * 2;
      int t = tv0 / V, v = tv0 % V;
      #pragma unroll
      for (int k = 0; k < 2; ++k) {
        #pragma unroll
        for (int c = 0; c < CC; ++c)
          inp[(c * TH + t) * IP + v] = accp[c][k];
        if (++v == V) { v = 0; ++t; }
      }
    }
    __syncthreads();

    // ---- preload next half's chunk 0 (in flight under P2(h=0))
    if (h == 0 && p1w) {
      const float* xpn = xp + TH * V;
      #pragma unroll
      for (int j = 0; j < 8; ++j)
        xv[j] = *reinterpret_cast<const float2*>(xpn + (size_t)j * TV);
    }

    // ---- P2h (tid < 256): acc[4][7]; per chk: 4 inp + 7 Af f4 reads, 112 FMA
    if (tid < 256) {
      float acc2[4][7];
      #pragma unroll
      for (int a = 0; a < 4; ++a)
        #pragma unroll
        for (int b = 0; b < 7; ++b) acc2[a][b] = 0.f;

      const float* ib = &inp[(cc2 * TH + tq) * IP];
      const float* ab = &Afs[(cc2 * V + u0) * AP];

      #pragma unroll
      for (int chk = 0; chk < 7; ++chk) {
        const f4 x0 = *reinterpret_cast<const f4*>(ib + 0 * 8 * IP + chk * 4);
        const f4 x1 = *reinterpret_cast<const f4*>(ib + 1 * 8 * IP + chk * 4);
        const f4 x2 = *reinterpret_cast<const f4*>(ib + 2 * 8 * IP + chk * 4);
        const f4 x3 = *reinterpret_cast<const f4*>(ib + 3 * 8 * IP + chk * 4);
        #pragma unroll
        for (int ku = 0; ku < 7; ++ku) {
          const f4 a = *reinterpret_cast<const f4*>(ab + ku * AP + chk * 4);
          acc2[0][ku] = fmaf(a.w, x0.w, fmaf(a.z, x0.z, fmaf(a.y, x0.y, fmaf(a.x, x0.x, acc2[0][ku]))));
          acc2[1][ku] = fmaf(a.w, x1.w, fmaf(a.z, x1.z, fmaf(a.y, x1.y, fmaf(a.x, x1.x, acc2[1][ku]))));
          acc2[2][ku] = fmaf(a.w, x2.w, fmaf(a.z, x2.z, fmaf(a.y, x2.y, fmaf(a.x, x2.x, acc2[2][ku]))));
          acc2[3][ku] = fmaf(a.w, x3.w, fmaf(a.z, x3.z, fmaf(a.y, x3.y, fmaf(a.x, x3.x, acc2[3][ku]))));
        }
      }

      float* ob = out + (((size_t)n * CO + (c0 + cc2)) * TT + h * TH) * V;
      #pragma unroll
      for (int ti = 0; ti < 4; ++ti) {
        const int t = tq + 8 * ti;
        #pragma unroll
        for (int ku = 0; ku < 7; ++ku)
          ob[t * V + u0 + ku] = acc2[ti][ku];
      }
    }
    if (h == 0) __syncthreads();   // P1(h=1) overwrites inp
  }
}

extern "C" void kernel_launch(void* const* d_in, const int* in_sizes, int n_in,
                              void* d_out, int out_size, void* d_ws, size_t ws_size,
                              hipStream_t stream) {
  (void)in_sizes; (void)n_in; (void)out_size; (void)ws_size;
  const float* x  = (const float*)d_in[0];
  const float* A  = (const float*)d_in[1];
  const float* w1 = (const float*)d_in[2];
  const float* b1 = (const float*)d_in[3];
  const float* w2 = (const float*)d_in[4];
  const float* b2 = (const float*)d_in[5];
  const float* w3 = (const float*)d_in[6];
  const float* b3 = (const float*)d_in[7];
  const float* wr = (const float*)d_in[8];
  const float* br = (const float*)d_in[9];
  float* out = (float*)d_out;
  float* ws  = (float*)d_ws;

  hipLaunchKernelGGL(k1_x12, dim3(NB), dim3(1024), 0, stream,
                     x, w1, b1, w2, b2, ws);
  hipLaunchKernelGGL(k2_fused, dim3(NB * CO / CC), dim3(512), 0, stream,
                     x, A, w3, b3, wr, br, ws, out);
}

// Round 11
// 145.612 us; speedup vs baseline: 2.7295x; 2.7295x over previous
//
#include <hip/hip_runtime.h>
#include <cmath>

namespace {
constexpr int NB  = 256;   // batch
constexpr int CI  = 64;    // in channels
constexpr int CO  = 64;    // out channels
constexpr int TT  = 64;    // time
constexpr int V   = 25;    // vertices
constexpr int REL = 8;     // rel channels
constexpr int TV  = TT * V;   // 1600
constexpr int CC  = 8;     // channels per fused block
constexpr int IP  = 28;    // inp row pad (16B-aligned rows)
constexpr int AP  = 28;    // Af row pad (16B-aligned rows)
}

typedef float f4 __attribute__((ext_vector_type(4)));

// ---------------------------------------------------------------------------
// K1: per-n temporal reduction -> x1,x2 (REL*V each) into ws. (unchanged)
// ---------------------------------------------------------------------------
__global__ __launch_bounds__(1024) void k1_x12(
    const float* __restrict__ x,
    const float* __restrict__ w1, const float* __restrict__ b1,
    const float* __restrict__ w2, const float* __restrict__ b2,
    float* __restrict__ ws) {
  const int n = blockIdx.x;
  const int tid = threadIdx.x;
  __shared__ __align__(16) float xs[8][TV];
  __shared__ float xsum[CI][V];
  __shared__ float w12[2][REL][CI];

  for (int idx = tid; idx < 2 * REL * CI; idx += 1024) {
    int half = idx / (REL * CI), rem = idx % (REL * CI);
    w12[half][rem / CI][rem % CI] = half ? w2[rem] : w1[rem];
  }

  const float4* xb = reinterpret_cast<const float4*>(x + (size_t)n * (CI * TV));
  float4* xsv = reinterpret_cast<float4*>(&xs[0][0]);
  constexpr int V4G = 8 * TV / 4;  // 3200

  for (int g = 0; g < 8; ++g) {
    __syncthreads();
    for (int idx = tid; idx < V4G; idx += 1024)
      xsv[idx] = xb[g * V4G + idx];
    __syncthreads();
    if (tid < 8 * V) {
      int ch = tid / V, v = tid % V;
      float acc = 0.f;
      #pragma unroll
      for (int t = 0; t < TT; ++t) acc += xs[ch][t * V + v];
      xsum[g * 8 + ch][v] = acc;
    }
  }
  __syncthreads();

  if (tid < 2 * REL * V) {
    int half = tid / (REL * V), rem = tid % (REL * V);
    int r = rem / V, v = rem % V;
    float a = 0.f;
    #pragma unroll
    for (int i = 0; i < CI; ++i) a = fmaf(w12[half][r][i], xsum[i][v], a);
    ws[(size_t)n * (2 * REL * V) + tid] = a * (1.f / TT) + (half ? b2[r] : b1[r]);
  }
}

// ---------------------------------------------------------------------------
// K2 fused == R7 structure (best known), ONE change: wr/br are read directly
// from global with block-uniform addresses inside P1 -> compiler emits s_load
// (scalar pipe + K$), eliminating the wrs LDS buffer and ~60% of the block's
// DS-pipe traffic (128 ds_read_b128/thread in P1 -> 0).
//   grid swizzle id=[n_hi5][cb3][n_lo3] -> 8 cb-blocks of an n on one XCD.
//   P0: zero inp pads; Af[8][25][28] built once (tanh inline, pad cols 0)
//   P1: inputs[8][64][28] in LDS (400 threads own float4 tv-columns)
//   P2: acc[4][7] per thread (t-rows tq+16*ti, u-rows 6*uq..6*uq+6),
//       v-chunk loop with immediate consumption; direct scatter stores.
// LDS 79744 B -> 2 blocks/CU.
// ---------------------------------------------------------------------------
__global__ __launch_bounds__(512, 4) void k2_fused(
    const float* __restrict__ x, const float* __restrict__ A,
    const float* __restrict__ w3, const float* __restrict__ b3,
    const float* __restrict__ wr, const float* __restrict__ br,
    const float* __restrict__ ws, float* __restrict__ out) {
  const int id  = blockIdx.x;
  const int n   = (id & 7) | ((id >> 3) & ~7);
  const int cb  = (id >> 3) & 7;
  const int c0  = cb * CC;
  const int tid = threadIdx.x;       // 0..511

  __shared__ __align__(16) float inp[CC * TT * IP];   // 57344 B
  __shared__ __align__(16) float Afs[CC * V * AP];    // 22400 B

  // ---- P0a: zero inp (pad columns v>=25 must be 0)
  {
    f4* iz = reinterpret_cast<f4*>(inp);
    #pragma unroll
    for (int k = 0; k < CC * TT * IP / 4 / 512; ++k)   // 7 stores
      iz[tid + k * 512] = (f4)0.f;
  }

  // ---- P0b: Af[cc][u][v] = A[u][v]+b3[c]+sum_r w3[c][r]*tanh(x1[r][u]-x2[r][v])
  //           pad columns (v>=25) = 0 (so f4 chunk 6 is safe)
  const float* x1n = ws + (size_t)n * (2 * REL * V);
  const float* x2n = x1n + REL * V;
  for (int idx = tid; idx < V * AP; idx += 512) {      // 700 tasks
    int u = idx / AP, v = idx % AP;
    if (v < V) {
      float t8[REL];
      #pragma unroll
      for (int r = 0; r < REL; ++r)
        t8[r] = tanhf(x1n[r * V + u] - x2n[r * V + v]);
      const float base = A[u * V + v];
      #pragma unroll
      for (int cc = 0; cc < CC; ++cc) {
        float acc = base + b3[c0 + cc];                // uniform -> s_load
        #pragma unroll
        for (int r = 0; r < REL; ++r)
          acc = fmaf(w3[(c0 + cc) * REL + r], t8[r], acc);  // uniform -> s_load
        Afs[(cc * V + u) * AP + v] = acc;
      }
    } else {
      #pragma unroll
      for (int cc = 0; cc < CC; ++cc)
        Afs[(cc * V + u) * AP + v] = 0.f;
    }
  }
  __syncthreads();

  // ---- P1: inputs tile (all t) into LDS. 400 threads own float4 tv-columns.
  //          weights via uniform global reads -> s_load (no LDS, no VMEM-vec).
  if (tid < TV / 4) {
    const float* xp = x + (size_t)n * (CI * TV) + tid * 4;
    float acc[CC][4];
    #pragma unroll
    for (int cc = 0; cc < CC; ++cc) {
      float b = br[c0 + cc];                           // uniform -> s_load
      acc[cc][0] = b; acc[cc][1] = b; acc[cc][2] = b; acc[cc][3] = b;
    }
    #pragma unroll 4
    for (int i = 0; i < CI; ++i) {
      float4 xv = *reinterpret_cast<const float4*>(xp + (size_t)i * TV);
      float w8[CC];
      #pragma unroll
      for (int cc = 0; cc < CC; ++cc)
        w8[cc] = wr[(size_t)(c0 + cc) * CI + i];       // uniform -> s_load
      #pragma unroll
      for (int cc = 0; cc < CC; ++cc) {
        acc[cc][0] = fmaf(w8[cc], xv.x, acc[cc][0]);
        acc[cc][1] = fmaf(w8[cc], xv.y, acc[cc][1]);
        acc[cc][2] = fmaf(w8[cc], xv.z, acc[cc][2]);
        acc[cc][3] = fmaf(w8[cc], xv.w, acc[cc][3]);
      }
    }
    int tv0 = tid * 4;
    int t = tv0 / V, v = tv0 % V;
    #pragma unroll
    for (int k = 0; k < 4; ++k) {
      #pragma unroll
      for (int cc = 0; cc < CC; ++cc)
        inp[(cc * TT + t) * IP + v] = acc[cc][k];
      if (++v == V) { v = 0; ++t; }
    }
  }
  __syncthreads();

  // ---- P2: thread = (cc, tq, uq). t-rows {tq, tq+16, tq+32, tq+48};
  //      u-rows {6*uq .. 6*uq+6} (overlap at 6/12/18 -> benign dup stores).
  //      acc[4][7] in regs; per v-chunk: 4 inp f4 + 7 Af f4, consumed at once.
  const int cc = tid >> 6;            // 0..7
  const int tq = (tid >> 2) & 15;     // 0..15
  const int uq = tid & 3;             // 0..3
  const int u0 = uq * 6;

  float acc[4][7];
  #pragma unroll
  for (int a = 0; a < 4; ++a)
    #pragma unroll
    for (int b = 0; b < 7; ++b) acc[a][b] = 0.f;

  const float* ib = &inp[(cc * TT + tq) * IP];
  const float* ab = &Afs[(cc * V + u0) * AP];

  #pragma unroll
  for (int chk = 0; chk < 7; ++chk) {
    const f4 x0 = *reinterpret_cast<const f4*>(ib + 0 * 16 * IP + chk * 4);
    const f4 x1 = *reinterpret_cast<const f4*>(ib + 1 * 16 * IP + chk * 4);
    const f4 x2 = *reinterpret_cast<const f4*>(ib + 2 * 16 * IP + chk * 4);
    const f4 x3 = *reinterpret_cast<const f4*>(ib + 3 * 16 * IP + chk * 4);
    #pragma unroll
    for (int ku = 0; ku < 7; ++ku) {
      const f4 a = *reinterpret_cast<const f4*>(ab + ku * AP + chk * 4);
      acc[0][ku] = fmaf(a.w, x0.w, fmaf(a.z, x0.z, fmaf(a.y, x0.y, fmaf(a.x, x0.x, acc[0][ku]))));
      acc[1][ku] = fmaf(a.w, x1.w, fmaf(a.z, x1.z, fmaf(a.y, x1.y, fmaf(a.x, x1.x, acc[1][ku]))));
      acc[2][ku] = fmaf(a.w, x2.w, fmaf(a.z, x2.z, fmaf(a.y, x2.y, fmaf(a.x, x2.x, acc[2][ku]))));
      acc[3][ku] = fmaf(a.w, x3.w, fmaf(a.z, x3.z, fmaf(a.y, x3.y, fmaf(a.x, x3.x, acc[3][ku]))));
    }
  }

  float* ob = out + ((size_t)n * CO + (c0 + cc)) * (TT * V);
  #pragma unroll
  for (int ti = 0; ti < 4; ++ti) {
    const int t = tq + 16 * ti;
    #pragma unroll
    for (int ku = 0; ku < 7; ++ku)
      ob[t * V + u0 + ku] = acc[ti][ku];
  }
}

extern "C" void kernel_launch(void* const* d_in, const int* in_sizes, int n_in,
                              void* d_out, int out_size, void* d_ws, size_t ws_size,
                              hipStream_t stream) {
  (void)in_sizes; (void)n_in; (void)out_size; (void)ws_size;
  const float* x  = (const float*)d_in[0];
  const float* A  = (const float*)d_in[1];
  const float* w1 = (const float*)d_in[2];
  const float* b1 = (const float*)d_in[3];
  const float* w2 = (const float*)d_in[4];
  const float* b2 = (const float*)d_in[5];
  const float* w3 = (const float*)d_in[6];
  const float* b3 = (const float*)d_in[7];
  const float* wr = (const float*)d_in[8];
  const float* br = (const float*)d_in[9];
  float* out = (float*)d_out;
  float* ws  = (float*)d_ws;

  hipLaunchKernelGGL(k1_x12, dim3(NB), dim3(1024), 0, stream,
                     x, w1, b1, w2, b2, ws);
  hipLaunchKernelGGL(k2_fused, dim3(NB * CO / CC), dim3(512), 0, stream,
                     x, A, w3, b3, wr, br, ws, out);
}